// Round 7
// baseline (195.045 us; speedup 1.0000x reference)
//
#include <hip/hip_runtime.h>
#include <hip/hip_bf16.h>
#include <math.h>

typedef __attribute__((ext_vector_type(8))) short short8;
typedef __attribute__((ext_vector_type(4))) float f32x4;
typedef unsigned short ushort_t;

#define B_  4
#define T_  4096
#define C_  1024
#define HS_ 128

// scale folded into q at GEMM epilogue: C^-0.5 * log2(e) -> scores in log2 units
#define QSCALE 0.04508422002778011f

__device__ __forceinline__ ushort_t f2bf(float f) {      // RNE
    unsigned int u = __float_as_uint(f);
    u = (u + 0x7FFFu + ((u >> 16) & 1u)) >> 16;
    return (ushort_t)u;
}
__device__ __forceinline__ ushort_t f2bf_fast(float f) { // positive, ~RNE
    return (ushort_t)((__float_as_uint(f) + 0x8000u) >> 16);
}
__device__ __forceinline__ float bf2f(ushort_t u) {
    return __uint_as_float(((unsigned)u) << 16);
}
__device__ __forceinline__ void async16(const void* g, void* l) {
    __builtin_amdgcn_global_load_lds(
        (const __attribute__((address_space(1))) unsigned int*)g,
        (__attribute__((address_space(3))) unsigned int*)l, 16, 0, 0);
}
__device__ __forceinline__ float exp2fast(float x) {
    return __builtin_amdgcn_exp2f(x);
}

// ---------------------------------------------------------------------------
// Kernel 1: W [1024][128] fp32 -> WT bf16 [m][h][k] via LDS transpose.
// ---------------------------------------------------------------------------
__global__ __launch_bounds__(256) void wt_kernel(
    const float* __restrict__ Wq, const float* __restrict__ Wk,
    const float* __restrict__ Wv, ushort_t* __restrict__ WT3)
{
    __shared__ ushort_t sWT[128 * 68];
    const int blk = blockIdx.x, tid = threadIdx.x;
    const int m = blk >> 4, slab = blk & 15;
    const float* __restrict__ W = (m == 0) ? Wq : (m == 1) ? Wk : Wv;
    const int kc = slab * 64;
    const int r = tid >> 2, h0 = (tid & 3) * 32;
#pragma unroll
    for (int j = 0; j < 8; ++j) {
        float4 wv = *(const float4*)(W + (size_t)(kc + r) * 128 + h0 + j * 4);
        sWT[(h0 + j * 4 + 0) * 68 + r] = f2bf(wv.x);
        sWT[(h0 + j * 4 + 1) * 68 + r] = f2bf(wv.y);
        sWT[(h0 + j * 4 + 2) * 68 + r] = f2bf(wv.z);
        sWT[(h0 + j * 4 + 3) * 68 + r] = f2bf(wv.w);
    }
    __syncthreads();
#pragma unroll
    for (int j = 0; j < 4; ++j) {
        int d = j * 256 + tid;
        int h = d >> 3, c8 = d & 7;
        short8 o;
#pragma unroll
        for (int e = 0; e < 8; ++e) o[e] = (short)sWT[h * 68 + c8 * 8 + e];
        *(short8*)(WT3 + (size_t)(m * 128 + h) * 1024 + kc + c8 * 8) = o;
    }
}

// ---------------------------------------------------------------------------
// Kernel 2: qkv = x @ W, fused fp32->bf16 in staging, 128x128 tile, BK=64,
// double-buffered (A regs+ds_write, B async16).  grid = (128, 3).
// ---------------------------------------------------------------------------
__global__ __launch_bounds__(256, 2) void qkv_gemm(
    const float* __restrict__ x, const ushort_t* __restrict__ WT3,
    ushort_t* __restrict__ q, ushort_t* __restrict__ k,
    ushort_t* __restrict__ vT)
{
    __shared__ ushort_t smem[32768];

    const int tid  = threadIdx.x;
    const int t0   = blockIdx.x * 128;
    const int mm   = blockIdx.y;
    const int w    = tid >> 6, lane = tid & 63;
    const int quad = lane >> 4, l15 = lane & 15;
    const int wr   = w >> 1, wc = w & 1;

    const ushort_t* __restrict__ WTm = WT3 + (size_t)mm * (128 * 1024);

    const int arow = tid >> 3, ac = tid & 7;
    const float* __restrict__ gx = x + (size_t)(t0 + arow) * C_ + ac * 8;
    const int aswz = ((ac ^ (arow & 7)) * 8);

    const ushort_t* gB[4];
    int bdst[4];
#pragma unroll
    for (int j = 0; j < 4; ++j) {
        int d = j * 256 + tid, row = d >> 3, c = d & 7;
        gB[j] = WTm + (size_t)row * C_ + ((c ^ (row & 7)) * 8);
        bdst[j] = d * 8;
    }

    f32x4 acc[4][4];
#pragma unroll
    for (int mt = 0; mt < 4; ++mt)
#pragma unroll
        for (int nt = 0; nt < 4; ++nt) acc[mt][nt] = (f32x4)0.f;

    float4 ar[4][2];
#pragma unroll
    for (int p = 0; p < 4; ++p) {
        ar[p][0] = *(const float4*)(gx + (size_t)(p * 32) * C_);
        ar[p][1] = *(const float4*)(gx + (size_t)(p * 32) * C_ + 4);
    }
#pragma unroll
    for (int j = 0; j < 4; ++j) async16(gB[j], &smem[8192 + bdst[j]]);
#pragma unroll
    for (int p = 0; p < 4; ++p) {
        short8 sv;
        sv[0]=f2bf(ar[p][0].x); sv[1]=f2bf(ar[p][0].y);
        sv[2]=f2bf(ar[p][0].z); sv[3]=f2bf(ar[p][0].w);
        sv[4]=f2bf(ar[p][1].x); sv[5]=f2bf(ar[p][1].y);
        sv[6]=f2bf(ar[p][1].z); sv[7]=f2bf(ar[p][1].w);
        *(short8*)&smem[(p * 32 + arow) * 64 + aswz] = sv;
    }
    __syncthreads();

    for (int it = 0; it < 16; ++it) {
        const int buf = it & 1, nb = buf ^ 1;
        const bool more = (it < 15);
        if (more) {
            const int kc = (it + 1) * 64;
#pragma unroll
            for (int p = 0; p < 4; ++p) {
                ar[p][0] = *(const float4*)(gx + (size_t)(p * 32) * C_ + kc);
                ar[p][1] = *(const float4*)(gx + (size_t)(p * 32) * C_ + kc + 4);
            }
#pragma unroll
            for (int j = 0; j < 4; ++j)
                async16(gB[j] + kc, &smem[nb * 16384 + 8192 + bdst[j]]);
        }
        const ushort_t* sA = &smem[buf * 16384];
        const ushort_t* sB = &smem[buf * 16384 + 8192];
#pragma unroll
        for (int kf = 0; kf < 2; ++kf) {
            short8 af[4], bf[4];
#pragma unroll
            for (int mt = 0; mt < 4; ++mt) {
                int row = wr * 64 + mt * 16 + l15;
                af[mt] = *(const short8*)&sA[row * 64 + (((kf * 4 + quad) ^ (row & 7)) * 8)];
            }
#pragma unroll
            for (int nt = 0; nt < 4; ++nt) {
                int row = wc * 64 + nt * 16 + l15;
                bf[nt] = *(const short8*)&sB[row * 64 + (((kf * 4 + quad) ^ (row & 7)) * 8)];
            }
#pragma unroll
            for (int mt = 0; mt < 4; ++mt)
#pragma unroll
                for (int nt = 0; nt < 4; ++nt)
                    acc[mt][nt] = __builtin_amdgcn_mfma_f32_16x16x32_bf16(
                        af[mt], bf[nt], acc[mt][nt], 0, 0, 0);
        }
        if (more) {
#pragma unroll
            for (int p = 0; p < 4; ++p) {
                short8 sv;
                sv[0]=f2bf(ar[p][0].x); sv[1]=f2bf(ar[p][0].y);
                sv[2]=f2bf(ar[p][0].z); sv[3]=f2bf(ar[p][0].w);
                sv[4]=f2bf(ar[p][1].x); sv[5]=f2bf(ar[p][1].y);
                sv[6]=f2bf(ar[p][1].z); sv[7]=f2bf(ar[p][1].w);
                *(short8*)&smem[nb * 16384 + (p * 32 + arow) * 64 + aswz] = sv;
            }
        }
        __syncthreads();
    }

    if (mm < 2) {
        ushort_t* __restrict__ outp = (mm == 0) ? q : k;
        const float s = (mm == 0) ? QSCALE : 1.0f;
        ushort_t* sE = &smem[0];            // 128 x 136
#pragma unroll
        for (int mt = 0; mt < 4; ++mt)
#pragma unroll
            for (int nt = 0; nt < 4; ++nt)
#pragma unroll
                for (int rr = 0; rr < 4; ++rr)
                    sE[(wr * 64 + mt * 16 + quad * 4 + rr) * 136
                       + wc * 64 + nt * 16 + l15] = f2bf(acc[mt][nt][rr] * s);
        __syncthreads();
#pragma unroll
        for (int j = 0; j < 8; ++j) {
            int d = j * 256 + tid;
            int row = d >> 4, cs = d & 15;
            *(short8*)(outp + (size_t)(t0 + row) * HS_ + cs * 8) =
                *(const short8*)&sE[row * 136 + cs * 8];
        }
    } else {
        ushort_t* sT = &smem[0];            // 128 x 132
#pragma unroll
        for (int mt = 0; mt < 4; ++mt)
#pragma unroll
            for (int nt = 0; nt < 4; ++nt)
#pragma unroll
                for (int rr = 0; rr < 4; ++rr)
                    sT[(wr * 64 + mt * 16 + quad * 4 + rr) * 132
                       + wc * 64 + nt * 16 + l15] = f2bf(acc[mt][nt][rr]);
        __syncthreads();
        const int b  = t0 >> 12;
        const int tl = t0 & (T_ - 1);
        const int hr = tid >> 1, th = tid & 1;
#pragma unroll
        for (int g = 0; g < 8; ++g) {
            short8 o;
#pragma unroll
            for (int e = 0; e < 8; ++e)
                o[e] = (short)sT[(th * 64 + g * 8 + e) * 132 + hr];
            *(short8*)(vT + ((size_t)(b * HS_) + hr) * T_ + tl + th * 64 + g * 8) = o;
        }
    }
}

// ---------------------------------------------------------------------------
// Kernel 3: causal flash attention.
// Q-tile 128 rows (4 waves x 32, wave-local).  K: 32-key sub-chunks, async16
// double-buffered with compile-time LDS bases (64-key super-chunk loop).
// V: read straight from L2 into registers (no LDS).  No softmax max (fixed
// shift cancels between numerator/denominator); l accumulated via a ones-MFMA.
// 512-key segments -> 576 blocks; partial O (bf16) + l -> combine.
// ---------------------------------------------------------------------------
__device__ __forceinline__ void attn_sub(
    const ushort_t* __restrict__ sK, ushort_t* __restrict__ sPw,
    const ushort_t* __restrict__ vTb, int kb, int qrow0,
    const short8 (&qf)[2][4], f32x4 (&O)[2][8], f32x4 (&O_l)[2],
    int quad, int l15)
{
    // ---- QK^T over 32 keys ----
    f32x4 S[2][2];
    S[0][0] = (f32x4)0.f; S[0][1] = (f32x4)0.f;
    S[1][0] = (f32x4)0.f; S[1][1] = (f32x4)0.f;
#pragma unroll
    for (int nt = 0; nt < 2; ++nt) {
        const int row = nt * 16 + l15;
#pragma unroll
        for (int kf = 0; kf < 4; ++kf) {
            short8 bf = *(const short8*)&sK[row * 128 + (((kf * 4 + quad) ^ l15) * 8)];
            S[0][nt] = __builtin_amdgcn_mfma_f32_16x16x32_bf16(qf[0][kf], bf, S[0][nt], 0, 0, 0);
            S[1][nt] = __builtin_amdgcn_mfma_f32_16x16x32_bf16(qf[1][kf], bf, S[1][nt], 0, 0, 0);
        }
    }
    // ---- causal mask (diagonal sub-chunks only) ----
    if (kb + 31 > qrow0) {
#pragma unroll
        for (int mt = 0; mt < 2; ++mt)
#pragma unroll
            for (int nt = 0; nt < 2; ++nt)
#pragma unroll
                for (int rr = 0; rr < 4; ++rr)
                    if (kb + nt * 16 + l15 > qrow0 + mt * 16 + quad * 4 + rr)
                        S[mt][nt][rr] = -1e30f;
    }
    // ---- V fragments straight from L2 (latency hidden by softmax) ----
    short8 vf[8];
#pragma unroll
    for (int nt = 0; nt < 8; ++nt)
        vf[nt] = *(const short8*)(vTb + (size_t)(nt * 16 + l15) * T_ + kb + quad * 8);
    // ---- softmax (no max subtraction; constant shift cancels) ----
#pragma unroll
    for (int mt = 0; mt < 2; ++mt)
#pragma unroll
        for (int nt = 0; nt < 2; ++nt)
#pragma unroll
            for (int rr = 0; rr < 4; ++rr)
                sPw[(mt * 16 + quad * 4 + rr) * 40 + nt * 16 + l15] =
                    f2bf_fast(exp2fast(S[mt][nt][rr]));
    // ---- PV + row-sums via ones-MFMA ----
    short8 ones;
#pragma unroll
    for (int e = 0; e < 8; ++e) ones[e] = (short)0x3F80;
#pragma unroll
    for (int mt = 0; mt < 2; ++mt) {
        short8 pf = *(short8*)&sPw[(mt * 16 + l15) * 40 + quad * 8];
        O_l[mt] = __builtin_amdgcn_mfma_f32_16x16x32_bf16(pf, ones, O_l[mt], 0, 0, 0);
#pragma unroll
        for (int nt = 0; nt < 8; ++nt)
            O[mt][nt] = __builtin_amdgcn_mfma_f32_16x16x32_bf16(pf, vf[nt], O[mt][nt], 0, 0, 0);
    }
}

__global__ __launch_bounds__(256) void attn_seg(
    const ushort_t* __restrict__ q, const ushort_t* __restrict__ k,
    const ushort_t* __restrict__ vT, ushort_t* __restrict__ Opart,
    float* __restrict__ lseg)
{
    __shared__ ushort_t smem[17408];   // K buf0 [0,4096) | K buf1 [4096,8192) | sP [8192,13312); epilogue: sE 128x136

    const int tid  = threadIdx.x;
    const int slot = blockIdx.x;
    int rr_ = blockIdx.x;
    const int bb = rr_ / 144;  rr_ -= bb * 144;
    int i = 0, ns;
    for (;;) { ns = (i + 4) >> 2; if (rr_ < ns) break; rr_ -= ns; ++i; }
    const int s    = rr_;
    const int qb   = i << 7;
    const int nsc  = (i + 1) << 1;           // 64-key super-chunks in causal range
    const int c0s  = (nsc * s) / ns;
    const int c1s  = (nsc * (s + 1)) / ns;

    const int w    = tid >> 6, lane = tid & 63;
    const int quad = lane >> 4, l15 = lane & 15;
    const size_t bT = (size_t)bb << 12;

    // K staging descriptors (swizzled source cols, linear LDS dest)
    const int kr0 = tid >> 4,          kc0 = tid & 15;
    const int kr1 = (tid + 256) >> 4,  kc1 = (tid + 256) & 15;
    const ushort_t* kp0 = k + (bT + (size_t)c0s * 64 + kr0) * HS_ + ((kc0 ^ (kr0 & 15)) * 8);
    const ushort_t* kp1 = k + (bT + (size_t)c0s * 64 + kr1) * HS_ + ((kc1 ^ (kr1 & 15)) * 8);

    const ushort_t* vTb = vT + (size_t)bb * HS_ * T_;
    ushort_t* sPw = smem + 8192 + w * 1280;
    const int qrow0 = qb + w * 32;

    short8 qf[2][4];
#pragma unroll
    for (int mt = 0; mt < 2; ++mt)
#pragma unroll
        for (int kf = 0; kf < 4; ++kf)
            qf[mt][kf] = *(const short8*)(
                q + (bT + qrow0 + mt * 16 + l15) * HS_ + kf * 32 + quad * 8);

    f32x4 O[2][8];
    f32x4 O_l[2];
#pragma unroll
    for (int mt = 0; mt < 2; ++mt) {
        O_l[mt] = (f32x4)0.f;
#pragma unroll
        for (int nt = 0; nt < 8; ++nt) O[mt][nt] = (f32x4)0.f;
    }

    // prologue: stage sub-chunk 2*c0s into buf0
    async16(kp0, smem + tid * 8);
    async16(kp1, smem + (tid + 256) * 8);
    kp0 += 32 * HS_; kp1 += 32 * HS_;
    __syncthreads();

    for (int cs = c0s; cs < c1s; ++cs) {
        // stage sub B -> buf1 (drains at the barrier after sub A's compute)
        async16(kp0, smem + 4096 + tid * 8);
        async16(kp1, smem + 4096 + (tid + 256) * 8);
        kp0 += 32 * HS_; kp1 += 32 * HS_;

        attn_sub(smem, sPw, vTb, cs * 64, qrow0, qf, O, O_l, quad, l15);
        __syncthreads();

        if (cs + 1 < c1s) {       // stage next sub A -> buf0
            async16(kp0, smem + tid * 8);
            async16(kp1, smem + (tid + 256) * 8);
            kp0 += 32 * HS_; kp1 += 32 * HS_;
        }
        attn_sub(smem + 4096, sPw, vTb, cs * 64 + 32, qrow0, qf, O, O_l, quad, l15);
        __syncthreads();
    }

    // ---- epilogue: bf16 partials via LDS coalesce, l from ones-MFMA ----
    ushort_t* sE = smem;               // 128 x 136
#pragma unroll
    for (int mt = 0; mt < 2; ++mt)
#pragma unroll
        for (int nt = 0; nt < 8; ++nt)
#pragma unroll
            for (int rr = 0; rr < 4; ++rr)
                sE[(w * 32 + mt * 16 + quad * 4 + rr) * 136 + nt * 16 + l15] =
                    f2bf(O[mt][nt][rr]);
    if (l15 == 0)
#pragma unroll
        for (int mt = 0; mt < 2; ++mt)
#pragma unroll
            for (int rr = 0; rr < 4; ++rr)
                lseg[slot * 128 + w * 32 + mt * 16 + quad * 4 + rr] = O_l[mt][rr];
    __syncthreads();
#pragma unroll
    for (int j = 0; j < 8; ++j) {
        int d = j * 256 + tid;
        int row = d >> 4, cs = d & 15;
        *(short8*)(Opart + (size_t)slot * 16384 + row * 128 + cs * 8) =
            *(const short8*)&sE[row * 136 + cs * 8];
    }
}

// ---------------------------------------------------------------------------
// Kernel 4: combine: out = (sum_s O_s) / (sum_s l_s).  grid = 512.
// ---------------------------------------------------------------------------
__global__ __launch_bounds__(256) void combine_kernel(
    const ushort_t* __restrict__ Opart, const float* __restrict__ lseg,
    float* __restrict__ out)
{
    const int blk  = blockIdx.x;
    const int tile = blk >> 2, rg = blk & 3;
    const int i    = tile & 31;
    int sb = (tile >> 5) * 144;
    for (int j = 0; j < i; ++j) sb += (j + 4) >> 2;
    const int ns  = (i + 4) >> 2;
    const int row = rg * 32 + (threadIdx.x >> 3);
    const int col = (threadIdx.x & 7) * 16;

    float den = 0.f;
    float acc[16];
#pragma unroll
    for (int e = 0; e < 16; ++e) acc[e] = 0.f;
    for (int s = 0; s < ns; ++s) {
        const int slot = sb + s;
        den += lseg[slot * 128 + row];
        const ushort_t* op = Opart + (size_t)slot * 16384 + row * 128 + col;
        short8 a = *(const short8*)op;
        short8 b = *(const short8*)(op + 8);
#pragma unroll
        for (int e = 0; e < 8; ++e) {
            acc[e]     += bf2f((ushort_t)a[e]);
            acc[8 + e] += bf2f((ushort_t)b[e]);
        }
    }
    const float inv = 1.0f / den;
    float* op = out + ((size_t)tile * 128 + row) * 128 + col;
#pragma unroll
    for (int g = 0; g < 4; ++g) {
        float4 v = make_float4(acc[g*4] * inv, acc[g*4+1] * inv,
                               acc[g*4+2] * inv, acc[g*4+3] * inv);
        *(float4*)(op + g * 4) = v;
    }
}

// ---------------------------------------------------------------------------
extern "C" void kernel_launch(void* const* d_in, const int* in_sizes, int n_in,
                              void* d_out, int out_size, void* d_ws, size_t ws_size,
                              hipStream_t stream)
{
    const float* x  = (const float*)d_in[0];
    const float* Wq = (const float*)d_in[1];
    const float* Wk = (const float*)d_in[2];
    const float* Wv = (const float*)d_in[3];
    float* out = (float*)d_out;

    ushort_t* WT3 = (ushort_t*)d_ws;               // 393,216 shorts
    ushort_t* q   = WT3 + 393216;                  // 2,097,152
    ushort_t* k   = q + 2097152;
    ushort_t* vT  = k + 2097152;                   // [B][HS][T]
    ushort_t* Opart = vT + 2097152;                // 576 slots x 16384 bf16
    float* lseg   = (float*)(Opart + 576 * 16384); // 73,728 floats

    wt_kernel<<<48, 256, 0, stream>>>(Wq, Wk, Wv, WT3);
    qkv_gemm<<<dim3(128, 3), 256, 0, stream>>>(x, WT3, q, k, vT);
    attn_seg<<<576, 256, 0, stream>>>(q, k, vT, Opart, lseg);
    combine_kernel<<<512, 256, 0, stream>>>(Opart, lseg, out);
}

// Round 8
// 169.321 us; speedup vs baseline: 1.1519x; 1.1519x over previous
//
#include <hip/hip_runtime.h>
#include <hip/hip_bf16.h>
#include <math.h>

typedef __attribute__((ext_vector_type(8))) short short8;
typedef __attribute__((ext_vector_type(4))) float f32x4;
typedef unsigned short ushort_t;

#define B_  4
#define T_  4096
#define C_  1024
#define HS_ 128

// scale folded into q at GEMM epilogue: C^-0.5 * log2(e) -> scores in log2 units
#define QSCALE 0.04508422002778011f

// per-tile segment counts (sum = 192 per batch -> grid 768 = 3 blocks/CU)
__device__ const unsigned char NS_[32] = {
    1,1,1,1,2,2,3,3,3,4,4,4,5,5,5,6,6,7,7,7,8,8,8,9,9,9,10,10,11,11,11,11};

__device__ __forceinline__ ushort_t f2bf(float f) {      // RNE
    unsigned int u = __float_as_uint(f);
    u = (u + 0x7FFFu + ((u >> 16) & 1u)) >> 16;
    return (ushort_t)u;
}
__device__ __forceinline__ ushort_t f2bf_fast(float f) { // positive, ~RNE
    return (ushort_t)((__float_as_uint(f) + 0x8000u) >> 16);
}
__device__ __forceinline__ float bf2f(ushort_t u) {
    return __uint_as_float(((unsigned)u) << 16);
}
__device__ __forceinline__ void async16(const void* g, void* l) {
    __builtin_amdgcn_global_load_lds(
        (const __attribute__((address_space(1))) unsigned int*)g,
        (__attribute__((address_space(3))) unsigned int*)l, 16, 0, 0);
}
__device__ __forceinline__ float exp2fast(float x) {
    return __builtin_amdgcn_exp2f(x);
}

// ---------------------------------------------------------------------------
// Kernel 1: W [1024][128] fp32 -> WT bf16 [m][h][k] via LDS transpose.
// ---------------------------------------------------------------------------
__global__ __launch_bounds__(256) void wt_kernel(
    const float* __restrict__ Wq, const float* __restrict__ Wk,
    const float* __restrict__ Wv, ushort_t* __restrict__ WT3)
{
    __shared__ ushort_t sWT[128 * 68];
    const int blk = blockIdx.x, tid = threadIdx.x;
    const int m = blk >> 4, slab = blk & 15;
    const float* __restrict__ W = (m == 0) ? Wq : (m == 1) ? Wk : Wv;
    const int kc = slab * 64;
    const int r = tid >> 2, h0 = (tid & 3) * 32;
#pragma unroll
    for (int j = 0; j < 8; ++j) {
        float4 wv = *(const float4*)(W + (size_t)(kc + r) * 128 + h0 + j * 4);
        sWT[(h0 + j * 4 + 0) * 68 + r] = f2bf(wv.x);
        sWT[(h0 + j * 4 + 1) * 68 + r] = f2bf(wv.y);
        sWT[(h0 + j * 4 + 2) * 68 + r] = f2bf(wv.z);
        sWT[(h0 + j * 4 + 3) * 68 + r] = f2bf(wv.w);
    }
    __syncthreads();
#pragma unroll
    for (int j = 0; j < 4; ++j) {
        int d = j * 256 + tid;
        int h = d >> 3, c8 = d & 7;
        short8 o;
#pragma unroll
        for (int e = 0; e < 8; ++e) o[e] = (short)sWT[h * 68 + c8 * 8 + e];
        *(short8*)(WT3 + (size_t)(m * 128 + h) * 1024 + kc + c8 * 8) = o;
    }
}

// ---------------------------------------------------------------------------
// Kernel 2: qkv = x @ W.  64x128 tile (4 waves of 16x128), BK=64, double-
// buffered (A regs+ds_write fused fp32->bf16, B async16).  grid = (256, 3)
// = 768 blocks = 3/CU exactly.  mm==0 -> q (pre-scaled); 1 -> k; 2 -> vT.
// ---------------------------------------------------------------------------
__global__ __launch_bounds__(256, 3) void qkv_gemm(
    const float* __restrict__ x, const ushort_t* __restrict__ WT3,
    ushort_t* __restrict__ q, ushort_t* __restrict__ k,
    ushort_t* __restrict__ vT)
{
    __shared__ ushort_t smem[24576];      // [2] x (A 4096 | B 8192 shorts)

    const int tid  = threadIdx.x;
    const int t0   = blockIdx.x * 64;
    const int mm   = blockIdx.y;
    const int w    = tid >> 6, lane = tid & 63;
    const int quad = lane >> 4, l15 = lane & 15;

    const ushort_t* __restrict__ WTm = WT3 + (size_t)mm * (128 * 1024);

    // A staging: pass p (0,1) -> row = p*32 + (tid>>3), col-chunk = tid&7
    const int arow = tid >> 3, ac = tid & 7;
    const float* __restrict__ gx = x + (size_t)(t0 + arow) * C_ + ac * 8;
    const int aswz = ((ac ^ (arow & 7)) * 8);

    // B staging: 4 chunks/thread via async16 (linear LDS dest, swizzled src)
    const ushort_t* gB[4];
    int bdst[4];
#pragma unroll
    for (int j = 0; j < 4; ++j) {
        int d = j * 256 + tid, row = d >> 3, c = d & 7;
        gB[j] = WTm + (size_t)row * C_ + ((c ^ (row & 7)) * 8);
        bdst[j] = 4096 + d * 8;
    }

    f32x4 acc[8];
#pragma unroll
    for (int nt = 0; nt < 8; ++nt) acc[nt] = (f32x4)0.f;

    float4 ar[2][2];
    // prologue: stage k-chunk 0 into buf 0
#pragma unroll
    for (int p = 0; p < 2; ++p) {
        ar[p][0] = *(const float4*)(gx + (size_t)(p * 32) * C_);
        ar[p][1] = *(const float4*)(gx + (size_t)(p * 32) * C_ + 4);
    }
#pragma unroll
    for (int j = 0; j < 4; ++j) async16(gB[j], &smem[bdst[j]]);
#pragma unroll
    for (int p = 0; p < 2; ++p) {
        short8 sv;
        sv[0]=f2bf(ar[p][0].x); sv[1]=f2bf(ar[p][0].y);
        sv[2]=f2bf(ar[p][0].z); sv[3]=f2bf(ar[p][0].w);
        sv[4]=f2bf(ar[p][1].x); sv[5]=f2bf(ar[p][1].y);
        sv[6]=f2bf(ar[p][1].z); sv[7]=f2bf(ar[p][1].w);
        *(short8*)&smem[(p * 32 + arow) * 64 + aswz] = sv;
    }
    __syncthreads();

    const int arow_q = w * 16 + l15;       // this lane's A row for fragments
    for (int it = 0; it < 16; ++it) {
        const int buf = it & 1, nb = buf ^ 1;
        const bool more = (it < 15);
        if (more) {
            const int kc = (it + 1) * 64;
#pragma unroll
            for (int p = 0; p < 2; ++p) {
                ar[p][0] = *(const float4*)(gx + (size_t)(p * 32) * C_ + kc);
                ar[p][1] = *(const float4*)(gx + (size_t)(p * 32) * C_ + kc + 4);
            }
#pragma unroll
            for (int j = 0; j < 4; ++j)
                async16(gB[j] + kc, &smem[nb * 12288 + bdst[j]]);
        }
        const ushort_t* sA = &smem[buf * 12288];
        const ushort_t* sB = &smem[buf * 12288 + 4096];
#pragma unroll
        for (int kf = 0; kf < 2; ++kf) {
            short8 af = *(const short8*)&sA[arow_q * 64 + (((kf * 4 + quad) ^ (arow_q & 7)) * 8)];
#pragma unroll
            for (int nt = 0; nt < 8; ++nt) {
                int row = nt * 16 + l15;
                short8 bf = *(const short8*)&sB[row * 64 + (((kf * 4 + quad) ^ (row & 7)) * 8)];
                acc[nt] = __builtin_amdgcn_mfma_f32_16x16x32_bf16(af, bf, acc[nt], 0, 0, 0);
            }
        }
        if (more) {
#pragma unroll
            for (int p = 0; p < 2; ++p) {
                short8 sv;
                sv[0]=f2bf(ar[p][0].x); sv[1]=f2bf(ar[p][0].y);
                sv[2]=f2bf(ar[p][0].z); sv[3]=f2bf(ar[p][0].w);
                sv[4]=f2bf(ar[p][1].x); sv[5]=f2bf(ar[p][1].y);
                sv[6]=f2bf(ar[p][1].z); sv[7]=f2bf(ar[p][1].w);
                *(short8*)&smem[nb * 12288 + (p * 32 + arow) * 64 + aswz] = sv;
            }
        }
        __syncthreads();
    }

    if (mm < 2) {
        ushort_t* __restrict__ outp = (mm == 0) ? q : k;
        const float s = (mm == 0) ? QSCALE : 1.0f;
        ushort_t* sE = &smem[0];            // 64 x 136
#pragma unroll
        for (int nt = 0; nt < 8; ++nt)
#pragma unroll
            for (int rr = 0; rr < 4; ++rr)
                sE[(w * 16 + quad * 4 + rr) * 136 + nt * 16 + l15] =
                    f2bf(acc[nt][rr] * s);
        __syncthreads();
#pragma unroll
        for (int j = 0; j < 4; ++j) {
            int d = j * 256 + tid;          // 1024 chunks (64 rows x 16)
            int row = d >> 4, cs = d & 15;
            *(short8*)(outp + (size_t)(t0 + row) * HS_ + cs * 8) =
                *(const short8*)&sE[row * 136 + cs * 8];
        }
    } else {
        ushort_t* sT = &smem[0];            // 64 x 132
#pragma unroll
        for (int nt = 0; nt < 8; ++nt)
#pragma unroll
            for (int rr = 0; rr < 4; ++rr)
                sT[(w * 16 + quad * 4 + rr) * 132 + nt * 16 + l15] =
                    f2bf(acc[nt][rr]);
        __syncthreads();
        const int bb = t0 >> 12;
        const int tl = t0 & (T_ - 1);
#pragma unroll
        for (int j = 0; j < 4; ++j) {
            int d = j * 256 + tid;          // 1024 chunks (128 h x 8 t-chunks)
            int h = d >> 3, t8 = d & 7;
            short8 o;
#pragma unroll
            for (int e = 0; e < 8; ++e)
                o[e] = (short)sT[(t8 * 8 + e) * 132 + h];
            *(short8*)(vT + ((size_t)(bb * HS_) + h) * T_ + tl + t8 * 8) = o;
        }
    }
}

// ---------------------------------------------------------------------------
// Kernel 3: causal flash attention.  Q-tile 128 rows (4 waves x 32, wave-
// local).  32-key chunks double-buffered: K via async16 (swizzled source),
// V^T via register prefetch + padded ds_write (R6-proven).  No softmax max
// (constant shift cancels); l via ones-MFMA.  Table-split segments ->
// 768 uniform blocks (3/CU).  1 barrier per chunk.
// ---------------------------------------------------------------------------
__global__ __launch_bounds__(256, 3) void attn_seg(
    const ushort_t* __restrict__ q, const ushort_t* __restrict__ k,
    const ushort_t* __restrict__ vT, ushort_t* __restrict__ Opart,
    float* __restrict__ lseg)
{
    __shared__ ushort_t smem[23552];       // 47.1 KB
    ushort_t* sKb = smem;                  // [2][4096] : 32 keys x 128 h, swz
    ushort_t* sVb = smem + 8192;           // [2][5120] : 128 h x 40
    ushort_t* sP  = smem + 18432;          // [4][1280] : 32 rows x 40

    const int tid  = threadIdx.x;
    const int slot = blockIdx.x;
    int r_ = blockIdx.x;
    const int bb = r_ / 192;  r_ -= bb * 192;
    int i = 0;
    while (r_ >= NS_[i]) { r_ -= NS_[i]; ++i; }
    const int s    = r_;
    const int ns   = NS_[i];
    const int qb   = i << 7;
    const int nkc  = (i + 1) << 2;           // 32-key chunks in causal range
    const int c0   = (nkc * s) / ns;
    const int c1   = (nkc * (s + 1)) / ns;

    const int w    = tid >> 6, lane = tid & 63;
    const int quad = lane >> 4, l15 = lane & 15;
    const size_t bT = (size_t)bb << 12;

    // staging descriptors
    const int kr0 = tid >> 4,          kc0 = tid & 15;
    const int kr1 = (tid + 256) >> 4,  kc1 = (tid + 256) & 15;
    const ushort_t* kp0 = k + (bT + (size_t)c0 * 32 + kr0) * HS_ + ((kc0 ^ (kr0 & 15)) * 8);
    const ushort_t* kp1 = k + (bT + (size_t)c0 * 32 + kr1) * HS_ + ((kc1 ^ (kr1 & 15)) * 8);
    const int vr0 = tid >> 2,          vc0 = tid & 3;
    const int vr1 = (tid + 256) >> 2,  vc1 = (tid + 256) & 3;
    const ushort_t* vp0 = vT + ((size_t)(bb * HS_) + vr0) * T_ + c0 * 32 + vc0 * 8;
    const ushort_t* vp1 = vT + ((size_t)(bb * HS_) + vr1) * T_ + c0 * 32 + vc1 * 8;
    const int vdst0 = vr0 * 40 + vc0 * 8;
    const int vdst1 = vr1 * 40 + vc1 * 8;

    // Q fragments (A-layout straight from global)
    short8 qf[2][4];
#pragma unroll
    for (int mt = 0; mt < 2; ++mt)
#pragma unroll
        for (int kf = 0; kf < 4; ++kf)
            qf[mt][kf] = *(const short8*)(
                q + (bT + qb + w * 32 + mt * 16 + l15) * HS_ + kf * 32 + quad * 8);

    f32x4 O[2][8];
    f32x4 O_l[2];
#pragma unroll
    for (int mt = 0; mt < 2; ++mt) {
        O_l[mt] = (f32x4)0.f;
#pragma unroll
        for (int nt = 0; nt < 8; ++nt) O[mt][nt] = (f32x4)0.f;
    }
    short8 ones;
#pragma unroll
    for (int e = 0; e < 8; ++e) ones[e] = (short)0x3F80;

    // prologue: stage chunk c0 into buf 0
    {
        short8 v0 = *(const short8*)vp0;
        short8 v1 = *(const short8*)vp1;
        async16(kp0, sKb + tid * 8);
        async16(kp1, sKb + (tid + 256) * 8);
        kp0 += 32 * HS_; kp1 += 32 * HS_; vp0 += 32; vp1 += 32;
        *(short8*)(sVb + vdst0) = v0;
        *(short8*)(sVb + vdst1) = v1;
    }
    __syncthreads();

    for (int c = c0; c < c1; ++c) {
        const int buf = (c - c0) & 1, nb = buf ^ 1;
        const int kb = c << 5;
        const bool more = (c + 1 < c1);
        short8 pv0, pv1;
        if (more) {                          // prefetch chunk c+1
            pv0 = *(const short8*)vp0;
            pv1 = *(const short8*)vp1;
            async16(kp0, sKb + nb * 4096 + tid * 8);
            async16(kp1, sKb + nb * 4096 + (tid + 256) * 8);
            kp0 += 32 * HS_; kp1 += 32 * HS_; vp0 += 32; vp1 += 32;
        }
        const ushort_t* sK = sKb + buf * 4096;
        const ushort_t* sV = sVb + buf * 5120;

        // ---- QK^T (scores in log2 units) ----
        f32x4 S[2][2];
        S[0][0] = (f32x4)0.f; S[0][1] = (f32x4)0.f;
        S[1][0] = (f32x4)0.f; S[1][1] = (f32x4)0.f;
#pragma unroll
        for (int nt = 0; nt < 2; ++nt) {
            int row = nt * 16 + l15;
#pragma unroll
            for (int kf = 0; kf < 4; ++kf) {
                short8 bf = *(const short8*)&sK[row * 128 + (((kf * 4 + quad) ^ l15) * 8)];
                S[0][nt] = __builtin_amdgcn_mfma_f32_16x16x32_bf16(qf[0][kf], bf, S[0][nt], 0, 0, 0);
                S[1][nt] = __builtin_amdgcn_mfma_f32_16x16x32_bf16(qf[1][kf], bf, S[1][nt], 0, 0, 0);
            }
        }
        // ---- causal mask (diagonal chunks only) ----
        if (kb + 31 > qb + w * 32) {
#pragma unroll
            for (int mt = 0; mt < 2; ++mt)
#pragma unroll
                for (int nt = 0; nt < 2; ++nt)
#pragma unroll
                    for (int rr = 0; rr < 4; ++rr)
                        if (kb + nt * 16 + l15 > qb + w * 32 + mt * 16 + quad * 4 + rr)
                            S[mt][nt][rr] = -1e30f;
        }
        // ---- softmax: p = exp2(S) (no max; shift cancels in combine) ----
#pragma unroll
        for (int mt = 0; mt < 2; ++mt)
#pragma unroll
            for (int nt = 0; nt < 2; ++nt)
#pragma unroll
                for (int rr = 0; rr < 4; ++rr)
                    sP[w * 1280 + (mt * 16 + quad * 4 + rr) * 40 + nt * 16 + l15] =
                        f2bf_fast(exp2fast(S[mt][nt][rr]));
        // ---- PV + row-sums via ones-MFMA ----
#pragma unroll
        for (int mt = 0; mt < 2; ++mt) {
            short8 pf = *(short8*)&sP[w * 1280 + (mt * 16 + l15) * 40 + quad * 8];
            O_l[mt] = __builtin_amdgcn_mfma_f32_16x16x32_bf16(pf, ones, O_l[mt], 0, 0, 0);
#pragma unroll
            for (int nt = 0; nt < 8; ++nt) {
                short8 vf = *(const short8*)&sV[(nt * 16 + l15) * 40 + quad * 8];
                O[mt][nt] = __builtin_amdgcn_mfma_f32_16x16x32_bf16(pf, vf, O[mt][nt], 0, 0, 0);
            }
        }
        // commit prefetched V into the other buffer
        if (more) {
            *(short8*)(sVb + nb * 5120 + vdst0) = pv0;
            *(short8*)(sVb + nb * 5120 + vdst1) = pv1;
        }
        __syncthreads();                     // one barrier per chunk
    }

    // ---- epilogue: bf16 partials via LDS coalesce, l from ones-MFMA ----
    ushort_t* sE = smem;                     // 128 x 136
#pragma unroll
    for (int mt = 0; mt < 2; ++mt)
#pragma unroll
        for (int nt = 0; nt < 8; ++nt)
#pragma unroll
            for (int rr = 0; rr < 4; ++rr)
                sE[(w * 32 + mt * 16 + quad * 4 + rr) * 136 + nt * 16 + l15] =
                    f2bf(O[mt][nt][rr]);
    if (l15 == 0)
#pragma unroll
        for (int mt = 0; mt < 2; ++mt)
#pragma unroll
            for (int rr = 0; rr < 4; ++rr)
                lseg[slot * 128 + w * 32 + mt * 16 + quad * 4 + rr] = O_l[mt][rr];
    __syncthreads();
#pragma unroll
    for (int j = 0; j < 8; ++j) {
        int d = j * 256 + tid;
        int row = d >> 4, cs = d & 15;
        *(short8*)(Opart + (size_t)slot * 16384 + row * 128 + cs * 8) =
            *(const short8*)&sE[row * 136 + cs * 8];
    }
}

// ---------------------------------------------------------------------------
// Kernel 4: combine: out = (sum_s O_s) / (sum_s l_s).  grid = 512.
// ---------------------------------------------------------------------------
__global__ __launch_bounds__(256) void combine_kernel(
    const ushort_t* __restrict__ Opart, const float* __restrict__ lseg,
    float* __restrict__ out)
{
    const int blk  = blockIdx.x;
    const int tile = blk >> 2, rg = blk & 3;
    const int i    = tile & 31;
    int sb = (tile >> 5) * 192;
    for (int j = 0; j < i; ++j) sb += NS_[j];
    const int ns  = NS_[i];
    const int row = rg * 32 + (threadIdx.x >> 3);
    const int col = (threadIdx.x & 7) * 16;

    float den = 0.f;
    float acc[16];
#pragma unroll
    for (int e = 0; e < 16; ++e) acc[e] = 0.f;
    for (int s = 0; s < ns; ++s) {
        const int slot = sb + s;
        den += lseg[slot * 128 + row];
        const ushort_t* op = Opart + (size_t)slot * 16384 + row * 128 + col;
        short8 a = *(const short8*)op;
        short8 b = *(const short8*)(op + 8);
#pragma unroll
        for (int e = 0; e < 8; ++e) {
            acc[e]     += bf2f((ushort_t)a[e]);
            acc[8 + e] += bf2f((ushort_t)b[e]);
        }
    }
    const float inv = 1.0f / den;
    float* op = out + ((size_t)tile * 128 + row) * 128 + col;
#pragma unroll
    for (int g = 0; g < 4; ++g) {
        float4 v = make_float4(acc[g*4] * inv, acc[g*4+1] * inv,
                               acc[g*4+2] * inv, acc[g*4+3] * inv);
        *(float4*)(op + g * 4) = v;
    }
}

// ---------------------------------------------------------------------------
extern "C" void kernel_launch(void* const* d_in, const int* in_sizes, int n_in,
                              void* d_out, int out_size, void* d_ws, size_t ws_size,
                              hipStream_t stream)
{
    const float* x  = (const float*)d_in[0];
    const float* Wq = (const float*)d_in[1];
    const float* Wk = (const float*)d_in[2];
    const float* Wv = (const float*)d_in[3];
    float* out = (float*)d_out;

    ushort_t* WT3 = (ushort_t*)d_ws;               // 393,216 shorts
    ushort_t* q   = WT3 + 393216;                  // 2,097,152
    ushort_t* k   = q + 2097152;
    ushort_t* vT  = k + 2097152;                   // [B][HS][T]
    ushort_t* Opart = vT + 2097152;                // 768 slots x 16384 bf16 (25.2 MB)
    float* lseg   = (float*)(Opart + 768 * 16384); // 98,304 floats

    wt_kernel<<<48, 256, 0, stream>>>(Wq, Wk, Wv, WT3);
    qkv_gemm<<<dim3(256, 3), 256, 0, stream>>>(x, WT3, q, k, vT);
    attn_seg<<<768, 256, 0, stream>>>(q, k, vT, Opart, lseg);
    combine_kernel<<<512, 256, 0, stream>>>(Opart, lseg, out);
}